// Round 1
// baseline (115.704 us; speedup 1.0000x reference)
//
#include <hip/hip_runtime.h>
#include <math.h>

#define NB 16
#define NC 64
#define NT 4096
#define NDEC 128

// alpha = exp(-1/5), computed in float64 then rounded to fp32 (matches reference)
#define ALPHA_F 0.81873075307798185867f
#define ONEMA_F 0.18126924692201814133f
// alpha^16 = exp(-3.2)
#define Q16_F   0.040762203978366216f

// One block per (b,c) row. Phase A: conv + dendritic_drive writes (coalesced,
// strided-t). Phase B: LIF linear-recurrence scan (16 steps/thread + Kogge-Stone).
__global__ __launch_bounds__(256) void conv_lif_kernel(
    const float* __restrict__ x,
    const float* __restrict__ w3, const float* __restrict__ b3,
    const float* __restrict__ w5, const float* __restrict__ b5,
    const float* __restrict__ rw, const float* __restrict__ rb,
    float* __restrict__ out)   // [pred 1024 | true_lat 1024 | act 1024 | dd 16M]
{
    __shared__ __align__(16) float s_x[4 + NT + 4];   // 4-float zero pad each side
    __shared__ float s_sum[NT + 256];                 // +1 pad per 16 (bank conflicts)
    __shared__ float s_scan[256];
    __shared__ int   s_wmin[4];

    const int bc  = blockIdx.x;
    const int c   = bc & (NC - 1);
    const int tid = threadIdx.x;

    // ---- stage x row into LDS ----
    if (tid < 4) { s_x[tid] = 0.f; s_x[4 + NT + tid] = 0.f; }
    {
        const float4* x4  = (const float4*)(x + (size_t)bc * NT);
        float4*       sx4 = (float4*)(s_x + 4);
        #pragma unroll
        for (int i = 0; i < 4; ++i) sx4[i * 256 + tid] = x4[i * 256 + tid];
    }

    // ---- per-channel weights (block-uniform) ----
    const float w30a = w3[(c*2+0)*3+0], w30b = w3[(c*2+0)*3+1], w30c = w3[(c*2+0)*3+2];
    const float w31a = w3[(c*2+1)*3+0], w31b = w3[(c*2+1)*3+1], w31c = w3[(c*2+1)*3+2];
    const float b30 = b3[c*2+0], b31 = b3[c*2+1];
    const float* w50p = w5 + (c*2+0)*5;
    const float* w51p = w5 + (c*2+1)*5;
    const float w50a=w50p[0], w50b=w50p[1], w50c=w50p[2], w50d=w50p[3], w50e=w50p[4];
    const float w51a=w51p[0], w51b=w51p[1], w51c=w51p[2], w51d=w51p[3], w51e=w51p[4];
    const float b50 = b5[c*2+0], b51 = b5[c*2+1];
    const float rw0 = rw[c*4+0], rw1 = rw[c*4+1], rw2 = rw[c*4+2], rw3 = rw[c*4+3];
    const float rbc = rb[c];

    __syncthreads();

    // ---- phase A: convs, dd writes (lane-coalesced), summed -> LDS ----
    float* dd = out + 3072 + (size_t)bc * (4 * NT);
    #pragma unroll 4
    for (int i = 0; i < 16; ++i) {
        int t = i * 256 + tid;
        float xm2 = s_x[t + 2];
        float xm1 = s_x[t + 3];
        float x0  = s_x[t + 4];
        float xp1 = s_x[t + 5];
        float xp2 = s_x[t + 6];
        float o30 = fmaf(w30c, xp1, fmaf(w30b, x0, fmaf(w30a, xm1, b30)));
        float o31 = fmaf(w31c, xp1, fmaf(w31b, x0, fmaf(w31a, xm1, b31)));
        float o50 = fmaf(w50e, xp2, fmaf(w50d, xp1, fmaf(w50c, x0,
                    fmaf(w50b, xm1, fmaf(w50a, xm2, b50)))));
        float o51 = fmaf(w51e, xp2, fmaf(w51d, xp1, fmaf(w51c, x0,
                    fmaf(w51b, xm1, fmaf(w51a, xm2, b51)))));
        dd[t]          = o30;
        dd[NT + t]     = o31;
        dd[2 * NT + t] = o50;
        dd[3 * NT + t] = o51;
        s_sum[t + (t >> 4)] = fmaf(rw3, o51, fmaf(rw2, o50,
                              fmaf(rw1, o31, fmaf(rw0, o30, rbc))));
    }
    __syncthreads();

    // ---- phase B: LIF scan. thread tid owns t in [tid*16, tid*16+16) ----
    const int t0 = tid * 16;
    float dv[16];
    #pragma unroll
    for (int j = 0; j < 16; ++j) dv[j] = s_sum[t0 + tid + j];  // padded index

    // local affine map applied to V=0: B_tid (A = alpha^16, constant)
    float V = 0.f;
    #pragma unroll
    for (int j = 0; j < 16; ++j)
        V = __fadd_rn(__fmul_rn(ALPHA_F, V), __fmul_rn(ONEMA_F, dv[j]));
    s_scan[tid] = V;
    __syncthreads();

    // Kogge-Stone inclusive scan: S_i = sum_j q^(i-j) B_j, q = alpha^16
    float coef = Q16_F;
    for (int off = 1; off < 256; off <<= 1) {
        float prev = (tid >= off) ? s_scan[tid - off] : 0.f;
        __syncthreads();
        s_scan[tid] = fmaf(coef, prev, s_scan[tid]);
        __syncthreads();
        coef *= coef;   // underflows to 0 after ~5 rounds; harmless
    }

    // re-run segment from exclusive prefix, detect first threshold crossing
    float Vin = (tid == 0) ? 0.f : s_scan[tid - 1];
    V = Vin;
    int firstt = NT;
    #pragma unroll
    for (int j = 0; j < 16; ++j) {
        V = __fadd_rn(__fmul_rn(ALPHA_F, V), __fmul_rn(ONEMA_F, dv[j]));
        if (V >= 1.0f && firstt == NT) firstt = t0 + j;
    }

    // block min-reduce of first crossing time
    int m = firstt;
    #pragma unroll
    for (int off = 32; off > 0; off >>= 1) m = min(m, __shfl_down(m, off));
    if ((tid & 63) == 0) s_wmin[tid >> 6] = m;
    __syncthreads();
    if (tid == 0) {
        int r = min(min(s_wmin[0], s_wmin[1]), min(s_wmin[2], s_wmin[3]));
        out[1024 + bc] = (float)r;   // true_latency (T if never fired)
    }
}

// One block per batch element: act -> gates -> MLP -> softplus/clip
__global__ __launch_bounds__(128) void head_kernel(
    const float* __restrict__ lat_scale,
    const float* __restrict__ og,
    const float* __restrict__ w1, const float* __restrict__ b1,
    const float* __restrict__ w2, const float* __restrict__ b2,
    float* __restrict__ out)
{
    __shared__ float act_s[NC];
    __shared__ float mixed_s[NC];
    __shared__ float h_s[NDEC];
    const int b   = blockIdx.x;
    const int tid = threadIdx.x;
    const float scale = fmaxf(lat_scale[0], 0.001f);

    if (tid < NC) {
        float tl = out[1024 + b * NC + tid];
        float a  = expf(-tl / scale);
        act_s[tid] = a;
        out[2048 + b * NC + tid] = a;        // act output
    }
    __syncthreads();

    if (tid < NC) {
        float mx = 0.f;
        #pragma unroll 8
        for (int cc = 0; cc < NC; ++cc) mx = fmaf(act_s[cc], og[tid * NC + cc], mx);
        mixed_s[tid] = mx;
    }
    __syncthreads();

    {   // all 128 threads: hidden layer
        float h = b1[tid];
        #pragma unroll 8
        for (int i = 0; i < NC; ++i) h = fmaf(mixed_s[i], w1[tid * NC + i], h);
        h_s[tid] = fmaxf(h, 0.f);
    }
    __syncthreads();

    if (tid < NC) {
        float r = b2[tid];
        #pragma unroll 8
        for (int j = 0; j < NDEC; ++j) r = fmaf(h_s[j], w2[tid * NDEC + j], r);
        // softplus = max(r,0) + log1p(exp(-|r|)); clip to [0, T]
        float sp = fmaxf(r, 0.f) + log1pf(expf(-fabsf(r)));
        out[b * NC + tid] = fminf(sp, (float)NT);
    }
}

extern "C" void kernel_launch(void* const* d_in, const int* in_sizes, int n_in,
                              void* d_out, int out_size, void* d_ws, size_t ws_size,
                              hipStream_t stream) {
    const float* x  = (const float*)d_in[0];
    const float* w3 = (const float*)d_in[1];
    const float* b3 = (const float*)d_in[2];
    const float* w5 = (const float*)d_in[3];
    const float* b5 = (const float*)d_in[4];
    const float* rw = (const float*)d_in[5];
    const float* rb = (const float*)d_in[6];
    const float* ls = (const float*)d_in[7];
    const float* og = (const float*)d_in[8];
    const float* w1 = (const float*)d_in[9];
    const float* b1 = (const float*)d_in[10];
    const float* w2 = (const float*)d_in[11];
    const float* b2 = (const float*)d_in[12];
    float* out = (float*)d_out;

    conv_lif_kernel<<<NB * NC, 256, 0, stream>>>(x, w3, b3, w5, b5, rw, rb, out);
    head_kernel<<<NB, 128, 0, stream>>>(ls, og, w1, b1, w2, b2, out);
}